// Round 7
// baseline (360.776 us; speedup 1.0000x reference)
//
#include <hip/hip_runtime.h>
#include <math.h>

#define DIN 640
#define KH 320
#define DH 1024
#define DOUT 128
#define CODEDIM 256
#define NE 8
#define NB 8
#define NT 1024
#define TAU_INV 10.0f
#define FEPS 1e-8f

// out layout: full_output[8*1024*1024], aux[1], div[1], ent[8], mean[8], std[8]
#define AUX_OFF  8388608
#define DIV_OFF  8388609
#define ENT_OFF  8388610
#define MEAN_OFF 8388618
#define STD_OFF  8388626

// LDS geometry (bytes). Strides %128==8 -> word-start 2r mod 32 -> 2-way (free).
#define XS_STRIDE 648                // 320*2+8, A half-tile row
#define HS_STRIDE 264                // 128*2+8, H chunk row
#define A_SZ 41472                   // 64*648
#define H_SZ 16896                   // 64*264
#define LDS_TOTAL (A_SZ + 2*H_SZ)   // 75,264 -> 2 blocks/CU

typedef __bf16 bf16;
typedef bf16 bf16x8 __attribute__((ext_vector_type(8)));
typedef float f32x16 __attribute__((ext_vector_type(16)));

__device__ __forceinline__ float gelu(float x) {
  return 0.5f * x * (1.0f + erff(x * 0.70710678118654752f));
}

// ---------------- block reduction helpers (blockDim multiple of 64) ----------
__device__ __forceinline__ float blk_sum(float v, float* sb) {
  #pragma unroll
  for (int o = 32; o > 0; o >>= 1) v += __shfl_down(v, o, 64);
  __syncthreads();
  if ((threadIdx.x & 63) == 0) sb[threadIdx.x >> 6] = v;
  __syncthreads();
  float tot = 0.f;
  int nw = blockDim.x >> 6;
  for (int i = 0; i < nw; ++i) tot += sb[i];
  return tot;
}

__device__ __forceinline__ float blk_max(float v, float* sb) {
  #pragma unroll
  for (int o = 32; o > 0; o >>= 1) v = fmaxf(v, __shfl_down(v, o, 64));
  __syncthreads();
  if ((threadIdx.x & 63) == 0) sb[threadIdx.x >> 6] = v;
  __syncthreads();
  float m = -3.0e38f;
  int nw = blockDim.x >> 6;
  for (int i = 0; i < nw; ++i) m = fmaxf(m, sb[i]);
  return m;
}

// ---------------- importance softmax + entropy/mean/std ---------------------
__global__ void k_imp(const float* __restrict__ fi, float* __restrict__ imp,
                      float* __restrict__ out) {
  __shared__ float sb[8];
  int e = blockIdx.x, tid = threadIdx.x;
  int d2v = tid + 512;
  float v0 = fi[e*DIN + tid] * 2.0f;          // /temp, temp = 0.5
  float v1 = fi[e*DIN + tid + 256] * 2.0f;
  float v2 = (d2v < DIN) ? fi[e*DIN + d2v] * 2.0f : -3.0e38f;
  float m = blk_max(fmaxf(v0, fmaxf(v1, v2)), sb);
  float e0 = expf(v0 - m), e1 = expf(v1 - m);
  float e2 = (d2v < DIN) ? expf(v2 - m) : 0.f;
  float s = blk_sum(e0 + e1 + e2, sb);
  float inv = 1.0f / s;
  float p0 = e0*inv, p1 = e1*inv, p2 = e2*inv;
  imp[e*DIN + tid] = p0;
  imp[e*DIN + tid + 256] = p1;
  if (d2v < DIN) imp[e*DIN + d2v] = p2;
  float ok2 = (d2v < DIN) ? 1.f : 0.f;
  float sp  = p0 + p1 + ok2*p2;
  float sp2 = p0*p0 + p1*p1 + ok2*p2*p2;
  float se  = p0*logf(p0 + FEPS) + p1*logf(p1 + FEPS) + ok2*p2*logf(p2 + FEPS);
  sp  = blk_sum(sp, sb);
  sp2 = blk_sum(sp2, sb);
  se  = blk_sum(se, sb);
  if (tid == 0) {
    out[ENT_OFF + e]  = -se;
    out[MEAN_OFF + e] = sp * (1.0f/DIN);
    float var = (sp2 - sp*sp*(1.0f/DIN)) * (1.0f/(DIN-1));
    out[STD_OFF + e]  = sqrtf(fmaxf(var, 0.f));
  }
}

// ---------------- anchor normalize + diversity loss --------------------------
__global__ void k_anchor_div(const float* __restrict__ ca, const float* __restrict__ fi,
                             float* __restrict__ anch, float* __restrict__ out) {
  __shared__ float sb[8];
  __shared__ float sd[256];
  int tid = threadIdx.x;
  for (int e = 0; e < NE; ++e) {
    float x = ca[e*CODEDIM + tid];
    float ss = blk_sum(x*x, sb);
    anch[e*CODEDIM + tid] = x / fmaxf(sqrtf(ss), 1e-12f);
  }
  // diversity: sim = fi @ fi^T, off-diag squared sum / 56
  int p = tid >> 2, q = tid & 3;     // pair p in 0..63, quarter q
  int i = p >> 3, j = p & 7;
  float dot = 0.f;
  for (int d = q*160; d < q*160 + 160; ++d) dot += fi[i*DIN + d] * fi[j*DIN + d];
  sd[tid] = dot;
  __syncthreads();
  if (tid < 64) {
    float s = sd[tid*4] + sd[tid*4+1] + sd[tid*4+2] + sd[tid*4+3];
    int ii = tid >> 3, jj = tid & 7;
    float val = (ii != jj) ? s*s : 0.f;
    #pragma unroll
    for (int o = 32; o > 0; o >>= 1) val += __shfl_down(val, o, 64);
    if (tid == 0) out[DIV_OFF] = val * (1.0f/56.0f);
  }
}

// -------- tiled transpose + f32->bf16 (+optional per-src-row scale) ----------
// src[e][R][C] -> dst[e][C][R]; dst[e][c][r] = src[e][r][c] * scale[e][r]
__global__ void k_transpose(const float* __restrict__ src, bf16* __restrict__ dst,
                            int R, int C, const float* __restrict__ scale) {
  __shared__ float tile[64][65];
  int c0 = blockIdx.x*64, r0 = blockIdx.y*64;
  int ee = blockIdx.z;
  const float* s = src + (size_t)ee*R*C;
  bf16* d = dst + (size_t)ee*C*R;
  int tx = threadIdx.x & 63, ty = threadIdx.x >> 6;
  #pragma unroll
  for (int p = 0; p < 16; ++p) {
    int r = p*4 + ty;
    tile[r][tx] = s[(size_t)(r0 + r)*C + c0 + tx];
  }
  __syncthreads();
  float sc = scale ? scale[(size_t)ee*R + r0 + tx] : 1.0f;
  #pragma unroll
  for (int p = 0; p < 16; ++p) {
    int cr = p*4 + ty;
    d[(size_t)(c0 + cr)*R + r0 + tx] = (bf16)(tile[tx][cr] * sc);
  }
}

// ---------------- h f32 -> bf16 (row-major, shared across experts) -----------
__global__ void k_h2b(const float* __restrict__ h, bf16* __restrict__ xb) {
  size_t i = (size_t)blockIdx.x*256 + threadIdx.x;   // 8 elements per thread
  const float4* p = (const float4*)(h + i*8);
  float4 v0 = p[0], v1 = p[1];
  bf16x8 o;
  o[0]=(bf16)v0.x; o[1]=(bf16)v0.y; o[2]=(bf16)v0.z; o[3]=(bf16)v0.w;
  o[4]=(bf16)v1.x; o[5]=(bf16)v1.y; o[6]=(bf16)v1.z; o[7]=(bf16)v1.w;
  *(bf16x8*)(xb + i*8) = o;
}

// ---------------- router: cosine logits + gumbel softmax ---------------------
__global__ void k_router(const float* __restrict__ ce, const float* __restrict__ gn,
                         const float* __restrict__ anch, float* __restrict__ ew) {
  __shared__ float anc[NE*CODEDIM];
  int tid = threadIdx.x;
  for (int i2 = tid; i2 < NE*CODEDIM; i2 += 256) anc[i2] = anch[i2];
  __syncthreads();
  int wv = tid >> 6, lane = tid & 63;
  int token = blockIdx.x*4 + wv;
  float4 x = *(const float4*)(ce + (size_t)token*CODEDIM + lane*4);
  float ss = x.x*x.x + x.y*x.y + x.z*x.z + x.w*x.w;
  #pragma unroll
  for (int o = 1; o < 64; o <<= 1) ss += __shfl_xor(ss, o, 64);
  float inv = 1.0f / fmaxf(sqrtf(ss), 1e-12f);
  const float* g = gn + (size_t)token*NE;
  float z[8];
  float m = -3.0e38f;
  #pragma unroll
  for (int e2 = 0; e2 < NE; ++e2) {
    const float* a = anc + e2*CODEDIM + lane*4;
    float d = x.x*a[0] + x.y*a[1] + x.z*a[2] + x.w*a[3];
    #pragma unroll
    for (int o = 1; o < 64; o <<= 1) d += __shfl_xor(d, o, 64);
    z[e2] = (d*inv + g[e2]) * TAU_INV;
    m = fmaxf(m, z[e2]);
  }
  float ssum = 0.f;
  float pz[8];
  #pragma unroll
  for (int e2 = 0; e2 < NE; ++e2) { pz[e2] = expf(z[e2] - m); ssum += pz[e2]; }
  float num = 0.f;
  #pragma unroll
  for (int e2 = 0; e2 < NE; ++e2) num = (lane == e2) ? pz[e2] : num;  // static idx
  if (lane < NE) ew[(size_t)token*NE + lane] = num / ssum;
}

// ---------------- fused MoE MLP: B-operands in registers ---------------------
// block = (expert e=bid&7 [XCD-pinned], 64-token M-tile). r6 showed LDS-B is
// structurally LDS-bound (2KB LDS/MFMA vs 8cyc MFMA). Here: W1/W2 fragments
// stream global->reg from XCD-local L2; only A (X-tile, K-halves, padded
// conflict-free) and Hs (128-col chunks, dbuf) live in LDS -> 0.5KB LDS/MFMA.
// 75.3KB LDS -> 2 blocks/CU (4 waves/SIMD); zero barriers inside K-sweeps.
// Per pass (512 DH-cols): wave owns 64 cols, acc 2x2 (64 VGPR); chunk phases
// overlap Hs-write(next) with GEMM2(cur). VGPR target <=128 (launch_bounds 4).
__global__ __launch_bounds__(512, 4)
void k_main(const bf16* __restrict__ xb, const bf16* __restrict__ w1t,
            const bf16* __restrict__ w2t,
            const float* __restrict__ b1, const float* __restrict__ b2,
            const float* __restrict__ ew, float* __restrict__ out) {
  __shared__ __align__(16) char L[LDS_TOTAL];
  const int bid = blockIdx.x;
  const int e = bid & 7;
  const int M0 = (bid >> 3) * 64;
  const int tid = threadIdx.x;
  const int lane = tid & 63, w = tid >> 6;
  const int l31 = lane & 31, hh = lane >> 5;
  const int rt2 = w >> 2, ct2 = w & 3;          // GEMM2: 2 row-tiles x 4 col-tiles
  const char* xby = (const char*)xb;
  const unsigned aA0 = (unsigned)(l31*XS_STRIDE + hh*16);
  const unsigned aA1 = aA0 + 32u*XS_STRIDE;
  f32x16 acc2 = {};

  for (int p = 0; p < 2; ++p) {
    f32x16 a00 = {}, a01 = {}, a10 = {}, a11 = {};
    const bf16* pB0 = w1t + ((size_t)(e*DH + p*512 + w*64 + l31))*DIN + hh*8;
    const bf16* pB1 = pB0 + 32*DIN;
    for (int kh = 0; kh < 2; ++kh) {
      __syncthreads();                    // prior readers of A / Hs done
      // stage A half: 64 rows x 320 cols bf16, padded stride (conflict-free)
      {
        const char* src = xby + (size_t)M0*(DIN*2) + kh*(KH*2);
        #pragma unroll
        for (int j = 0; j < 5; ++j) {
          int fc = j*512 + tid;           // 2560 chunks of 16B
          int row = fc / 40, cc = fc - row*40;
          bf16x8 v = *(const bf16x8*)(src + (size_t)row*(DIN*2) + cc*16);
          *(bf16x8*)(L + row*XS_STRIDE + cc*16) = v;
        }
      }
      __syncthreads();
      const bf16* q0 = pB0 + kh*KH;
      const bf16* q1 = pB1 + kh*KH;
      #pragma unroll 2
      for (int ks = 0; ks < KH/16; ++ks) {
        bf16x8 b0 = *(const bf16x8*)(q0 + 16*ks);   // global (L2) -> reg
        bf16x8 b1f = *(const bf16x8*)(q1 + 16*ks);
        bf16x8 af0 = *(const bf16x8*)(L + aA0 + 32u*ks);
        bf16x8 af1 = *(const bf16x8*)(L + aA1 + 32u*ks);
        a00 = __builtin_amdgcn_mfma_f32_32x32x16_bf16(af0, b0, a00, 0, 0, 0);
        a10 = __builtin_amdgcn_mfma_f32_32x32x16_bf16(af1, b0, a10, 0, 0, 0);
        a01 = __builtin_amdgcn_mfma_f32_32x32x16_bf16(af0, b1f, a01, 0, 0, 0);
        a11 = __builtin_amdgcn_mfma_f32_32x32x16_bf16(af1, b1f, a11, 0, 0, 0);
      }
    }
    // chunk phases: region r: owners (w>>1 == r) GELU+write Hs[r&1];
    // all waves GEMM2 chunk r-1 from Hs[(r-1)&1]. Buffers alternate; 1 bar each.
    for (int r = 0; r < 5; ++r) {
      __syncthreads();
      if (r < 4 && (w >> 1) == r) {
        float bb0 = b1[e*DH + p*512 + w*64 + l31];
        float bb1 = b1[e*DH + p*512 + w*64 + 32 + l31];
        char* Hb = L + A_SZ + (r & 1)*H_SZ;
        int c0b = ((w & 1)*64 + l31)*2;
        #pragma unroll
        for (int rr = 0; rr < 16; ++rr) {
          int crow = (rr & 3) + 8*(rr >> 2) + 4*hh;
          char* h0 = Hb + crow*HS_STRIDE;
          char* h1 = Hb + (32 + crow)*HS_STRIDE;
          *(bf16*)(h0 + c0b)      = (bf16)gelu(a00[rr] + bb0);
          *(bf16*)(h1 + c0b)      = (bf16)gelu(a10[rr] + bb0);
          *(bf16*)(h0 + c0b + 64) = (bf16)gelu(a01[rr] + bb1);
          *(bf16*)(h1 + c0b + 64) = (bf16)gelu(a11[rr] + bb1);
        }
      }
      if (r >= 1) {
        int gc = p*4 + (r - 1);
        const char* Hb = L + A_SZ + ((r - 1) & 1)*H_SZ;
        const bf16* pB2 = w2t + (size_t)(e*DOUT + ct2*32 + l31)*DH + gc*128 + hh*8;
        const unsigned aH = (unsigned)((rt2*32 + l31)*HS_STRIDE + hh*16);
        #pragma unroll
        for (int kk = 0; kk < 8; ++kk) {
          bf16x8 a2  = *(const bf16x8*)(Hb + aH + 32u*kk);
          bf16x8 b2f = *(const bf16x8*)(pB2 + 16*kk);
          acc2 = __builtin_amdgcn_mfma_f32_32x32x16_bf16(a2, b2f, acc2, 0, 0, 0);
        }
      }
    }
  }
  // output: +b2, *gate, f32 store
  float bb2 = b2[e*DOUT + ct2*32 + l31];
  #pragma unroll
  for (int rr = 0; rr < 16; ++rr) {
    int crow = (rr & 3) + 8*(rr >> 2) + 4*hh;
    int m = M0 + rt2*32 + crow;
    float gate = ew[(size_t)m*NE + e];
    out[(size_t)m*(NE*DOUT) + e*DOUT + ct2*32 + l31] = (acc2[rr] + bb2) * gate;
  }
}

// ---------------- expert counts + partial sums --------------------------------
__global__ void k_counts(const float* __restrict__ ew, float* __restrict__ counts,
                         float* __restrict__ partials) {
  __shared__ float sb[4];
  int g2 = blockIdx.x*256 + threadIdx.x;   // (t,e) flat, 0..8191
  float c = 0.f;
  #pragma unroll
  for (int b = 0; b < NB; ++b) c += ew[b*(NT*NE) + g2];
  counts[g2] = c;
  float tot = blk_sum(c, sb);
  if (threadIdx.x == 0) partials[blockIdx.x] = tot;
}

// ---------------- aux loss ----------------------------------------------------
__global__ void k_aux(const float* __restrict__ counts, const float* __restrict__ partials,
                      float* __restrict__ out) {
  __shared__ float sb[4];
  int tid = threadIdx.x;
  float pv = (tid < 32) ? partials[tid] : 0.f;
  float total = blk_sum(pv, sb);
  float invt = 1.0f / (total + FEPS);
  float sq = 0.f, ent = 0.f;
  for (int i2 = tid; i2 < NT*NE; i2 += 256) {
    float c = counts[i2];
    sq += c*c;
    float ld = c * invt;
    ent -= ld * logf(ld + FEPS);
  }
  sq = blk_sum(sq, sb);
  ent = blk_sum(ent, sb);
  if (tid == 0) {
    float var = (sq - total*total*(1.0f/(NT*NE))) * (1.0f/(NT*NE - 1));
    float stdv = sqrtf(fmaxf(var, 0.f));
    float ment = 0.f;
    #pragma unroll
    for (int e2 = 0; e2 < NE; ++e2) ment += out[ENT_OFF + e2];
    ment *= (1.0f/NE);
    out[AUX_OFF] = 0.5f*(stdv + ent) + 0.01f*ment;
  }
}

// ---------------- launch ------------------------------------------------------
extern "C" void kernel_launch(void* const* d_in, const int* in_sizes, int n_in,
                              void* d_out, int out_size, void* d_ws, size_t ws_size,
                              hipStream_t stream) {
  const float* h  = (const float*)d_in[0];
  const float* ce = (const float*)d_in[1];
  const float* gn = (const float*)d_in[2];
  const float* ca = (const float*)d_in[3];
  const float* fi = (const float*)d_in[4];
  const float* W1 = (const float*)d_in[5];
  const float* b1 = (const float*)d_in[6];
  const float* W2 = (const float*)d_in[7];
  const float* b2 = (const float*)d_in[8];
  float* out = (float*)d_out;
  char* ws = (char*)d_ws;
  // ws layout (bytes)
  bf16*  w1t      = (bf16*)(ws);                 // [E][DH][DIN] bf16 (imp-folded): 10,485,760
  bf16*  w2t      = (bf16*)(ws + 10485760);      // [E][DOUT][DH] bf16: 2,097,152
  bf16*  xbuf     = (bf16*)(ws + 12582912);      // [8192][640] bf16: 10,485,760
  float* imp      = (float*)(ws + 23068672);     // [E][DIN]: 20,480
  float* anch     = (float*)(ws + 23089152);     // [E][CODE]: 8,192
  float* ew       = (float*)(ws + 23097344);     // [B][T][E]: 262,144
  float* counts   = (float*)(ws + 23359488);     // [T*E]: 32,768
  float* partials = (float*)(ws + 23392256);     // [32]

  k_imp<<<dim3(8), dim3(256), 0, stream>>>(fi, imp, out);
  k_anchor_div<<<dim3(1), dim3(256), 0, stream>>>(ca, fi, anch, out);
  k_transpose<<<dim3(16, 10, 8), dim3(256), 0, stream>>>(W1, w1t, 640, 1024, imp);
  k_transpose<<<dim3(2, 16, 8), dim3(256), 0, stream>>>(W2, w2t, 1024, 128, nullptr);
  k_h2b<<<dim3(2560), dim3(256), 0, stream>>>(h, xbuf);
  k_router<<<dim3(2048), dim3(256), 0, stream>>>(ce, gn, anch, ew);
  k_main<<<dim3(1024), dim3(512), 0, stream>>>(xbuf, w1t, w2t, b1, b2, ew, out);
  k_counts<<<dim3(32), dim3(256), 0, stream>>>(ew, counts, partials);
  k_aux<<<dim3(1), dim3(256), 0, stream>>>(counts, partials, out);
}